// Round 1
// 2553.101 us; speedup vs baseline: 1.7861x; 1.7861x over previous
//
#include <hip/hip_runtime.h>
#include <hip/hip_fp16.h>

typedef _Float16 half8 __attribute__((ext_vector_type(8)));
typedef float f32x4 __attribute__((ext_vector_type(4)));
typedef unsigned u32x4 __attribute__((ext_vector_type(4)));
typedef unsigned long long u64;

#define B_ 256
#define SEQ_ 512
#define D_ 256
#define H_ 1024
#define C_ 10
#define S_ 511
#define KB_ 40      // K=1280 / 32
#define NPK_ 2048   // packed output cols per direction (g|i interleaved per 64)
#define NTF_ 128    // NPK/16 fine n-tiles
#define LP_ 84      // LDS row stride (floats): 86,016B total -> forces 1 block/CU (co-residency guarantee)

// ---- workspace byte offsets ----
#define WPK_HALVES (2*KB_*NTF_*512)                    // 5,242,880 halves
#define EMBH_OFF   (WPK_HALVES*2)                      // 10,485,760
#define EMBH_HALVES (SEQ_*D_)                          // 131,072
#define HPK_OFF    (EMBH_OFF + EMBH_HALVES*2)          // 10,747,904
#define HPK_PER_PAR (2*32*16*64*8)                     // 524,288 halves per parity (both dirs)
#define HFIN_OFF   (HPK_OFF + 2*HPK_PER_PAR*2)         // 12,845,056
#define HFIN_FLOATS (2*B_*H_)
#define BIAS_OFF   (HFIN_OFF + HFIN_FLOATS*4)
#define BAR_OFF    (BIAS_OFF + 2*NPK_*4)               // 8 groups x 32 producers x 16-word pad
#define BAR_WORDS  (8*32*16)
#define XT_OFF     (BAR_OFF + BAR_WORDS*4)             // transposed x: [SEQ][B] ints
#define XT_INTS    (SEQ_*B_)
#define XCD_OFF    (XT_OFF + XT_INTS*4)                // per-block XCC id (runtime co-location check)
#define XCD_WORDS  256

__device__ __forceinline__ float fast_sigm(float x) {
    return __builtin_amdgcn_rcpf(1.f + __builtin_amdgcn_exp2f(-1.442695041f * x));
}
__device__ __forceinline__ float fast_tanh(float x) {
    return 1.f - 2.f * __builtin_amdgcn_rcpf(1.f + __builtin_amdgcn_exp2f(2.885390082f * x));
}
__device__ __forceinline__ half8 load_h_uc(const _Float16* p) {
    u64 two[2];
    two[0] = __hip_atomic_load((const u64*)p,     __ATOMIC_RELAXED, __HIP_MEMORY_SCOPE_SYSTEM);
    two[1] = __hip_atomic_load((const u64*)p + 1, __ATOMIC_RELAXED, __HIP_MEMORY_SCOPE_SYSTEM);
    half8 r; __builtin_memcpy(&r, two, 16); return r;
}

// Pack fp32 weights -> fp16 MFMA B-fragment-direct layout, emb -> fp16, biases packed,
// x -> transposed xT[t][m], zero barrier flags + xcd-id slots (ws re-poisoned before every call).
__global__ void convert_kernel(
    const int* __restrict__ x, const float* __restrict__ emb,
    const float* __restrict__ Wgx_f, const float* __restrict__ Wgh_f, const float* __restrict__ bg_f,
    const float* __restrict__ Wix_f, const float* __restrict__ Wih_f, const float* __restrict__ bi_f,
    const float* __restrict__ Wgx_b, const float* __restrict__ Wgh_b, const float* __restrict__ bg_b,
    const float* __restrict__ Wix_b, const float* __restrict__ Wih_b, const float* __restrict__ bi_b,
    _Float16* __restrict__ Wpk, _Float16* __restrict__ embh, float* __restrict__ biaspk,
    unsigned* __restrict__ bar, int* __restrict__ xT, unsigned* __restrict__ xcdid)
{
    int idx = blockIdx.x * 256 + threadIdx.x;
    if (idx < WPK_HALVES) {
        int j = idx & 7;
        int L = (idx >> 3) & 63;
        int rest = idx >> 9;
        int ntf = rest & (NTF_ - 1);
        int rest2 = rest >> 7;
        int kb = rest2 % KB_;
        int d  = rest2 / KB_;
        int k = kb*32 + ((L >> 4) << 3) + j;
        int p = (ntf << 4) + (L & 15);
        int gate = (p >> 5) & 1;
        int u = ((p >> 6) << 5) + (p & 31);
        float v;
        if (k < D_) {
            const float* W = d ? (gate ? Wix_b : Wgx_b) : (gate ? Wix_f : Wgx_f);
            v = W[k*H_ + u];
        } else {
            const float* W = d ? (gate ? Wih_b : Wgh_b) : (gate ? Wih_f : Wgh_f);
            v = W[(k - D_)*H_ + u];
        }
        Wpk[idx] = (_Float16)v;
    } else if (idx < WPK_HALVES + EMBH_HALVES) {
        int i2 = idx - WPK_HALVES;
        embh[i2] = (_Float16)emb[i2];
    } else if (idx < WPK_HALVES + EMBH_HALVES + 2*NPK_) {
        int i3 = idx - (WPK_HALVES + EMBH_HALVES);
        int d = i3 >> 11;
        int p = i3 & (NPK_ - 1);
        int gate = (p >> 5) & 1;
        int u = ((p >> 6) << 5) + (p & 31);
        const float* bsrc = d ? (gate ? bi_b : bg_b) : (gate ? bi_f : bg_f);
        biaspk[i3] = bsrc[u];
    } else if (idx < WPK_HALVES + EMBH_HALVES + 2*NPK_ + BAR_WORDS) {
        bar[idx - (WPK_HALVES + EMBH_HALVES + 2*NPK_)] = 0u;
    } else if (idx < WPK_HALVES + EMBH_HALVES + 2*NPK_ + BAR_WORDS + XT_INTS) {
        int i5 = idx - (WPK_HALVES + EMBH_HALVES + 2*NPK_ + BAR_WORDS);
        int t = i5 >> 8;
        int m = i5 & (B_ - 1);
        xT[i5] = x[m*SEQ_ + t];
    } else if (idx < WPK_HALVES + EMBH_HALVES + 2*NPK_ + BAR_WORDS + XT_INTS + XCD_WORDS) {
        xcdid[idx - (WPK_HALVES + EMBH_HALVES + 2*NPK_ + BAR_WORDS + XT_INTS)] = 0u;
    }
}

// Fast-path L2-scope exchange helpers. Group blocks share one XCD (runtime-verified),
// so plain stores land in the shared L2 and sc0 loads (L1-bypass, L2-hit) see them.
// Volatile-asm ordering: poll-asm precedes load-asms precedes waitcnt-asm;
// sched_barrier(0) after each counted waitcnt fences MFMA hoisting (rule #18).
#define ISSUE_PAIR(buf, pr)                                                                     \
    { _Pragma("unroll")                                                                         \
      for (int j2 = 0; j2 < 2; ++j2) {                                                          \
        _Pragma("unroll")                                                                       \
        for (int mt = 0; mt < 4; ++mt) {                                                        \
            const _Float16* hp = hrd + (size_t)(((8*w + (pr)*2 + j2)*16 + (mtblk*4 + mt))*64 + lane)*8; \
            asm volatile("global_load_dwordx4 %0, %1, off sc0" : "=v"(buf[j2*4+mt]) : "v"(hp)); \
        } } }

#define MFMA_PAIR(buf, pr)                                                                      \
    { _Pragma("unroll")                                                                         \
      for (int j2 = 0; j2 < 2; ++j2)                                                            \
        _Pragma("unroll")                                                                       \
        for (int mt = 0; mt < 4; ++mt)                                                          \
          _Pragma("unroll")                                                                     \
          for (int nt = 0; nt < 4; ++nt)                                                        \
            acc[mt][nt] = __builtin_amdgcn_mfma_f32_16x16x32_f16(buf[j2*4+mt], wfh[(pr)*2+j2][nt], acc[mt][nt], 0, 0, 0); }

// Persistent kernel: all 511 timesteps, both directions.
// blockIdx = ntb*8 + group, group = dir*4 + mtblk. 1 block/CU forced by LDS size.
// W + c-state in registers. h exchanged via the group's shared XCD L2 when the
// runtime XCC_ID check confirms co-location; else via system-scope UC (original path).
__global__ __launch_bounds__(256, 1) void persistent_kernel(
    const int* __restrict__ xT, const _Float16* __restrict__ embh,
    const _Float16* __restrict__ Wpk, const float* __restrict__ biaspk,
    _Float16* __restrict__ hpk, float* __restrict__ hfinal,
    unsigned* __restrict__ bar, unsigned* __restrict__ xcdid)
{
    __shared__ float lds[4][64][LP_];

    int group = blockIdx.x & 7;
    int dir   = group >> 2;
    int mtblk = group & 3;
    int ntb   = blockIdx.x >> 3;
    int w    = threadIdx.x >> 6;
    int lane = threadIdx.x & 63;
    int q    = lane >> 4;
    int c16  = lane & 15;
    int u0   = q * 8;               // epilogue: 8 consecutive units per thread

    unsigned* gflags = bar + group * (32*16);

    // ---- publish this block's XCD id (system scope, one-time) ----
    unsigned myxcc;
    asm volatile("s_getreg_b32 %0, hwreg(HW_REG_XCC_ID)" : "=s"(myxcc));
    myxcc &= 15u;
    if (threadIdx.x == 0)
        __hip_atomic_store(&xcdid[blockIdx.x], myxcc | 0x100u, __ATOMIC_RELAXED, __HIP_MEMORY_SCOPE_SYSTEM);

    const _Float16* Wd = Wpk + (size_t)dir * (KB_*NTF_*512);

    // ---- preload W fragments into registers ----
    // wave w: x-kbs {2w, 2w+1}, h-kbs {8+8w .. 15+8w}
    half8 wfx[2][4], wfh[8][4];
    #pragma unroll
    for (int kx = 0; kx < 2; ++kx) {
        #pragma unroll
        for (int nt = 0; nt < 4; ++nt)
            wfx[kx][nt] = *(const half8*)(Wd + (((size_t)(2*w + kx)*NTF_ + (ntb*4 + nt))*64 + lane)*8);
    }
    #pragma unroll
    for (int i = 0; i < 8; ++i) {
        #pragma unroll
        for (int nt = 0; nt < 4; ++nt)
            wfh[i][nt] = *(const half8*)(Wd + (((size_t)(8 + 8*w + i)*NTF_ + (ntb*4 + nt))*64 + lane)*8);
    }

    // ---- preload epilogue biases ----
    float bgr[8], bir[8];
    #pragma unroll
    for (int j = 0; j < 8; ++j) {
        bgr[j] = biaspk[dir*NPK_ + ntb*64 + u0 + j];
        bir[j] = biaspk[dir*NPK_ + ntb*64 + 32 + u0 + j];
    }

    // ---- runtime co-location check: my group's 32 producers all on my XCD? ----
    bool fast;
    {
        unsigned idv = myxcc | 0x100u;   // lanes >= 32: passes both checks
        for (;;) {
            if (lane < 32)
                idv = __hip_atomic_load(&xcdid[lane*8 + group], __ATOMIC_RELAXED, __HIP_MEMORY_SCOPE_SYSTEM);
            if (__all(idv >= 0x100u)) break;
            __builtin_amdgcn_s_sleep(1);
        }
        fast = __all(idv == (myxcc | 0x100u));  // group-consistent decision
    }

    // ---- c-state in registers: thread owns (m = mtblk*64+w*16+c16, u = ntb*32+u0+j) ----
    float creg[8];
    #pragma unroll
    for (int j = 0; j < 8; ++j) creg[j] = 0.f;

    #pragma unroll 1
    for (int t = 0; t < S_; ++t) {
        const _Float16* hrd = hpk + (size_t)(t & 1) * HPK_PER_PAR + dir*(32*16*64*8);
        _Float16*       hwr = hpk + (size_t)((t & 1) ^ 1) * HPK_PER_PAR + dir*(32*16*64*8);
        int t_eff = dir ? (S_ - 1 - t) : t;

        int xr[4];
        #pragma unroll
        for (int mt = 0; mt < 4; ++mt)
            xr[mt] = xT[t_eff*B_ + mtblk*64 + mt*16 + c16];

        f32x4 acc[4][4];
        #pragma unroll
        for (int a = 0; a < 4; ++a)
            #pragma unroll
            for (int b = 0; b < 4; ++b) {
                acc[a][b][0] = 0.f; acc[a][b][1] = 0.f; acc[a][b][2] = 0.f; acc[a][b][3] = 0.f;
            }

        // ---- x-part (independent of h): overlaps producer wait ----
        #pragma unroll
        for (int kx = 0; kx < 2; ++kx) {
            int kb = 2*w + kx;
            half8 a[4];
            #pragma unroll
            for (int mt = 0; mt < 4; ++mt)
                a[mt] = *(const half8*)(embh + xr[mt]*D_ + kb*32 + q*8);
            #pragma unroll
            for (int mt = 0; mt < 4; ++mt) {
                #pragma unroll
                for (int nt = 0; nt < 4; ++nt)
                    acc[mt][nt] = __builtin_amdgcn_mfma_f32_16x16x32_f16(a[mt], wfx[kx][nt], acc[mt][nt], 0, 0, 0);
            }
        }

        if (t > 0) {
            unsigned gen = (unsigned)t;
            if (fast) {
                // ---- L2-scope wait: poll per-wave flags (4 words per producer line) ----
                u32x4 fv = {gen, gen, gen, gen};
                for (;;) {
                    if (lane < 32) {
                        const unsigned* fp = gflags + lane*16;
                        asm volatile("global_load_dwordx4 %0, %1, off sc0\n\ts_waitcnt vmcnt(0)"
                                     : "=v"(fv) : "v"(fp) : "memory");
                    }
                    if (__all(fv[0] >= gen && fv[1] >= gen && fv[2] >= gen && fv[3] >= gen)) break;
                    __builtin_amdgcn_s_sleep(1);
                }
                // ---- h-part: sc0 (L2-hit) loads, 2-deep pipelined with counted vmcnt ----
                half8 aE[8], aO[8];
                ISSUE_PAIR(aE, 0);
                ISSUE_PAIR(aO, 1);
                asm volatile("s_waitcnt vmcnt(8)" ::: "memory");
                __builtin_amdgcn_sched_barrier(0);
                MFMA_PAIR(aE, 0);
                ISSUE_PAIR(aE, 2);
                asm volatile("s_waitcnt vmcnt(8)" ::: "memory");
                __builtin_amdgcn_sched_barrier(0);
                MFMA_PAIR(aO, 1);
                ISSUE_PAIR(aO, 3);
                asm volatile("s_waitcnt vmcnt(8)" ::: "memory");
                __builtin_amdgcn_sched_barrier(0);
                MFMA_PAIR(aE, 2);
                asm volatile("s_waitcnt vmcnt(0)" ::: "memory");
                __builtin_amdgcn_sched_barrier(0);
                MFMA_PAIR(aO, 3);
            } else {
                // ---- system-scope fallback (original path) ----
                unsigned v = gen;
                for (;;) {
                    if (lane < 32)
                        v = __hip_atomic_load(&gflags[lane*16], __ATOMIC_RELAXED, __HIP_MEMORY_SCOPE_SYSTEM);
                    if (__all(v >= gen)) break;
                    __builtin_amdgcn_s_sleep(1);
                }
                #pragma unroll
                for (int i = 0; i < 8; ++i) {
                    int kb2 = 8*w + i;
                    half8 a[4];
                    #pragma unroll
                    for (int mt = 0; mt < 4; ++mt)
                        a[mt] = load_h_uc(hrd + (size_t)((kb2*16 + (mtblk*4 + mt))*64 + lane)*8);
                    #pragma unroll
                    for (int mt = 0; mt < 4; ++mt) {
                        #pragma unroll
                        for (int nt = 0; nt < 4; ++nt)
                            acc[mt][nt] = __builtin_amdgcn_mfma_f32_16x16x32_f16(a[mt], wfh[i][nt], acc[mt][nt], 0, 0, 0);
                    }
                }
            }
        }

        // K-split partials -> LDS
        #pragma unroll
        for (int mt = 0; mt < 4; ++mt) {
            #pragma unroll
            for (int nt = 0; nt < 4; ++nt) {
                #pragma unroll
                for (int r = 0; r < 4; ++r)
                    lds[w][mt*16 + q*4 + r][nt*16 + c16] = acc[mt][nt][r];
            }
        }
        __syncthreads();

        // Epilogue: thread -> (m_loc = w*16 + c16, units u0..u0+7). Cols: g = u_loc, i = 32+u_loc.
        {
            int mloc = w*16 + c16;
            int mg   = mtblk*64 + mloc;
            half8 hv;
            float hf[8];
            #pragma unroll
            for (int j = 0; j < 8; ++j) {
                float zg = lds[0][mloc][u0 + j] + lds[1][mloc][u0 + j]
                         + lds[2][mloc][u0 + j] + lds[3][mloc][u0 + j] + bgr[j];
                float zi = lds[0][mloc][32 + u0 + j] + lds[1][mloc][32 + u0 + j]
                         + lds[2][mloc][32 + u0 + j] + lds[3][mloc][32 + u0 + j] + bir[j];
                float g  = fast_tanh(zg);
                float ii = fast_sigm(zi);
                float cn = ii * (g + creg[j]);
                creg[j] = cn;
                float h = fast_tanh(cn) * ii;
                hv[j] = (_Float16)h;
                hf[j] = h;
            }
            // publish h into A-fragment layout
            _Float16* base = hwr + ((size_t)((ntb*16 + mtblk*4 + w)*64 + lane) * 8);
            if (fast) {
                // plain store -> lands in the group's shared XCD L2
                asm volatile("global_store_dwordx4 %0, %1, off" :: "v"(base), "v"(hv) : "memory");
            } else {
                u64 two[2];
                __builtin_memcpy(two, &hv, 16);
                __hip_atomic_store((u64*)base,     two[0], __ATOMIC_RELAXED, __HIP_MEMORY_SCOPE_SYSTEM);
                __hip_atomic_store((u64*)base + 1, two[1], __ATOMIC_RELAXED, __HIP_MEMORY_SCOPE_SYSTEM);
            }
            if (t == S_ - 1) {
                #pragma unroll
                for (int j = 0; j < 8; ++j)
                    hfinal[dir*(B_*H_) + mg*H_ + ntb*32 + u0 + j] = hf[j];
            }
        }

        // ---- publish completion flag ----
        if (t != S_ - 1) {
            if (fast) {
                // per-wave flag: only this wave's store must drain; no block barrier on the
                // signal path. LDS-protect barrier moved after the publish.
                asm volatile("s_waitcnt vmcnt(0)" ::: "memory");
                if (lane == 0) {
                    unsigned* fp = &gflags[ntb*16 + w];
                    unsigned val = (unsigned)(t + 1);
                    asm volatile("global_store_dword %0, %1, off" :: "v"(fp), "v"(val) : "memory");
                }
                __syncthreads();
            } else {
                __builtin_amdgcn_s_waitcnt(0x0F70);   // vmcnt(0)
                __syncthreads();
                if (threadIdx.x == 0)
                    __hip_atomic_store(&gflags[ntb*16], (unsigned)(t + 1), __ATOMIC_RELAXED, __HIP_MEMORY_SCOPE_SYSTEM);
            }
        }
    }
}

// out[b][c] = [hf|hb] @ Wp + bp
__global__ void proj_kernel(const float* __restrict__ hfinal,
                            const float* __restrict__ Wp, const float* __restrict__ bp,
                            float* __restrict__ out)
{
    int b = blockIdx.x;
    int lane = threadIdx.x;
    float s[C_];
    #pragma unroll
    for (int c = 0; c < C_; ++c) s[c] = 0.f;
    for (int j = lane; j < 2*H_; j += 64) {
        float hv = (j < H_) ? hfinal[b*H_ + j] : hfinal[B_*H_ + b*H_ + (j - H_)];
        const float* wr = Wp + j*C_;
        #pragma unroll
        for (int c = 0; c < C_; ++c) s[c] += hv * wr[c];
    }
    #pragma unroll
    for (int off = 32; off > 0; off >>= 1) {
        #pragma unroll
        for (int c = 0; c < C_; ++c) s[c] += __shfl_down(s[c], off);
    }
    if (lane == 0) {
        #pragma unroll
        for (int c = 0; c < C_; ++c) out[b*C_ + c] = s[c] + bp[c];
    }
}

extern "C" void kernel_launch(void* const* d_in, const int* in_sizes, int n_in,
                              void* d_out, int out_size, void* d_ws, size_t ws_size,
                              hipStream_t stream)
{
    const int*   x     = (const int*)d_in[0];
    const float* emb   = (const float*)d_in[1];
    const float* Wgx_f = (const float*)d_in[2];
    const float* Wgh_f = (const float*)d_in[3];
    const float* bg_f  = (const float*)d_in[4];
    const float* Wix_f = (const float*)d_in[5];
    const float* Wih_f = (const float*)d_in[6];
    const float* bi_f  = (const float*)d_in[7];
    const float* Wgx_b = (const float*)d_in[8];
    const float* Wgh_b = (const float*)d_in[9];
    const float* bg_b  = (const float*)d_in[10];
    const float* Wix_b = (const float*)d_in[11];
    const float* Wih_b = (const float*)d_in[12];
    const float* bi_b  = (const float*)d_in[13];
    const float* Wp    = (const float*)d_in[14];
    const float* bp    = (const float*)d_in[15];
    float* out = (float*)d_out;

    char* ws = (char*)d_ws;
    _Float16* Wpk    = (_Float16*)(ws + 0);
    _Float16* embh   = (_Float16*)(ws + EMBH_OFF);
    _Float16* hpk    = (_Float16*)(ws + HPK_OFF);
    float*    hfinal = (float*)(ws + HFIN_OFF);
    float*    biaspk = (float*)(ws + BIAS_OFF);
    unsigned* bar    = (unsigned*)(ws + BAR_OFF);
    int*      xT     = (int*)(ws + XT_OFF);
    unsigned* xcdid  = (unsigned*)(ws + XCD_OFF);

    int total = WPK_HALVES + EMBH_HALVES + 2*NPK_ + BAR_WORDS + XT_INTS + XCD_WORDS;
    convert_kernel<<<(total + 255)/256, 256, 0, stream>>>(
        x, emb, Wgx_f, Wgh_f, bg_f, Wix_f, Wih_f, bi_f,
        Wgx_b, Wgh_b, bg_b, Wix_b, Wih_b, bi_b, Wpk, embh, biaspk, bar, xT, xcdid);

    persistent_kernel<<<256, 256, 0, stream>>>(xT, embh, Wpk, biaspk, hpk, hfinal, bar, xcdid);

    proj_kernel<<<B_, 64, 0, stream>>>(hfinal, Wp, bp, out);
}

// Round 5
// 2540.570 us; speedup vs baseline: 1.7949x; 1.0049x over previous
//
#include <hip/hip_runtime.h>
#include <hip/hip_fp16.h>

typedef _Float16 half8 __attribute__((ext_vector_type(8)));
typedef float f32x4 __attribute__((ext_vector_type(4)));
typedef unsigned u32x4 __attribute__((ext_vector_type(4)));
typedef unsigned long long u64;

#define B_ 256
#define SEQ_ 512
#define D_ 256
#define H_ 1024
#define C_ 10
#define S_ 511
#define KB_ 40      // K=1280 / 32
#define NPK_ 2048   // packed output cols per direction (g|i interleaved per 64)
#define NTF_ 128    // NPK/16 fine n-tiles
#define LP_ 84      // LDS row stride (floats): 86,016B total -> forces 1 block/CU (co-residency guarantee)

// ---- workspace byte offsets ----
#define WPK_HALVES (2*KB_*NTF_*512)                    // 5,242,880 halves
#define EMBH_OFF   (WPK_HALVES*2)                      // 10,485,760
#define EMBH_HALVES (SEQ_*D_)                          // 131,072
#define HPK_OFF    (EMBH_OFF + EMBH_HALVES*2)          // 10,747,904
#define HPK_PER_PAR (2*32*16*64*8)                     // 524,288 halves per parity (both dirs)
#define HFIN_OFF   (HPK_OFF + 2*HPK_PER_PAR*2)         // 12,845,056
#define HFIN_FLOATS (2*B_*H_)
#define BIAS_OFF   (HFIN_OFF + HFIN_FLOATS*4)
#define BAR_OFF    (BIAS_OFF + 2*NPK_*4)               // 8 groups x 32 producers x 16-word pad
#define BAR_WORDS  (8*32*16)
#define XT_OFF     (BAR_OFF + BAR_WORDS*4)             // transposed x: [SEQ][B] ints
#define XT_INTS    (SEQ_*B_)
#define XCD_OFF    (XT_OFF + XT_INTS*4)                // per-block XCC id (runtime co-location check)
#define XCD_WORDS  256

__device__ __forceinline__ float fast_sigm(float x) {
    return __builtin_amdgcn_rcpf(1.f + __builtin_amdgcn_exp2f(-1.442695041f * x));
}
__device__ __forceinline__ float fast_tanh(float x) {
    return 1.f - 2.f * __builtin_amdgcn_rcpf(1.f + __builtin_amdgcn_exp2f(2.885390082f * x));
}
__device__ __forceinline__ half8 load_h_uc(const _Float16* p) {
    u64 two[2];
    two[0] = __hip_atomic_load((const u64*)p,     __ATOMIC_RELAXED, __HIP_MEMORY_SCOPE_SYSTEM);
    two[1] = __hip_atomic_load((const u64*)p + 1, __ATOMIC_RELAXED, __HIP_MEMORY_SCOPE_SYSTEM);
    half8 r; __builtin_memcpy(&r, two, 16); return r;
}

// Pack fp32 weights -> fp16 MFMA B-fragment-direct layout, emb -> fp16, biases packed,
// x -> transposed xT[t][m], zero barrier flags + xcd-id slots (ws is re-poisoned before every call).
__global__ void convert_kernel(
    const int* __restrict__ x, const float* __restrict__ emb,
    const float* __restrict__ Wgx_f, const float* __restrict__ Wgh_f, const float* __restrict__ bg_f,
    const float* __restrict__ Wix_f, const float* __restrict__ Wih_f, const float* __restrict__ bi_f,
    const float* __restrict__ Wgx_b, const float* __restrict__ Wgh_b, const float* __restrict__ bg_b,
    const float* __restrict__ Wix_b, const float* __restrict__ Wih_b, const float* __restrict__ bi_b,
    _Float16* __restrict__ Wpk, _Float16* __restrict__ embh, float* __restrict__ biaspk,
    unsigned* __restrict__ bar, int* __restrict__ xT, unsigned* __restrict__ xcdid)
{
    int idx = blockIdx.x * 256 + threadIdx.x;
    if (idx < WPK_HALVES) {
        int j = idx & 7;
        int L = (idx >> 3) & 63;
        int rest = idx >> 9;
        int ntf = rest & (NTF_ - 1);
        int rest2 = rest >> 7;
        int kb = rest2 % KB_;
        int d  = rest2 / KB_;
        int k = kb*32 + ((L >> 4) << 3) + j;
        int p = (ntf << 4) + (L & 15);
        int gate = (p >> 5) & 1;
        int u = ((p >> 6) << 5) + (p & 31);
        float v;
        if (k < D_) {
            const float* W = d ? (gate ? Wix_b : Wgx_b) : (gate ? Wix_f : Wgx_f);
            v = W[k*H_ + u];
        } else {
            const float* W = d ? (gate ? Wih_b : Wgh_b) : (gate ? Wih_f : Wgh_f);
            v = W[(k - D_)*H_ + u];
        }
        Wpk[idx] = (_Float16)v;
    } else if (idx < WPK_HALVES + EMBH_HALVES) {
        int i2 = idx - WPK_HALVES;
        embh[i2] = (_Float16)emb[i2];
    } else if (idx < WPK_HALVES + EMBH_HALVES + 2*NPK_) {
        int i3 = idx - (WPK_HALVES + EMBH_HALVES);
        int d = i3 >> 11;
        int p = i3 & (NPK_ - 1);
        int gate = (p >> 5) & 1;
        int u = ((p >> 6) << 5) + (p & 31);
        const float* bsrc = d ? (gate ? bi_b : bg_b) : (gate ? bi_f : bg_f);
        biaspk[i3] = bsrc[u];
    } else if (idx < WPK_HALVES + EMBH_HALVES + 2*NPK_ + BAR_WORDS) {
        bar[idx - (WPK_HALVES + EMBH_HALVES + 2*NPK_)] = 0u;
    } else if (idx < WPK_HALVES + EMBH_HALVES + 2*NPK_ + BAR_WORDS + XT_INTS) {
        int i5 = idx - (WPK_HALVES + EMBH_HALVES + 2*NPK_ + BAR_WORDS);
        int t = i5 >> 8;
        int m = i5 & (B_ - 1);
        xT[i5] = x[m*SEQ_ + t];
    } else if (idx < WPK_HALVES + EMBH_HALVES + 2*NPK_ + BAR_WORDS + XT_INTS + XCD_WORDS) {
        xcdid[idx - (WPK_HALVES + EMBH_HALVES + 2*NPK_ + BAR_WORDS + XT_INTS)] = 0u;
    }
}

// Fast-path L2-scope exchange helpers. Group blocks share one XCD (runtime-verified),
// so plain stores land in the shared L2 and sc0 loads (L1-bypass, L2-hit) see them.
// Volatile-asm ordering: poll-asm precedes load-asms precedes waitcnt-asm;
// sched_barrier(0) after each counted waitcnt fences MFMA hoisting (rule #18).
#define ISSUE_PAIR(buf, pr)                                                                     \
    { _Pragma("unroll")                                                                         \
      for (int j2 = 0; j2 < 2; ++j2) {                                                          \
        _Pragma("unroll")                                                                       \
        for (int mt = 0; mt < 4; ++mt) {                                                        \
            const _Float16* hp = hrd + (size_t)(((8*w + (pr)*2 + j2)*16 + (mtblk*4 + mt))*64 + lane)*8; \
            asm volatile("global_load_dwordx4 %0, %1, off sc0" : "=v"(buf[j2*4+mt]) : "v"(hp)); \
        } } }

#define MFMA_PAIR(buf, pr)                                                                      \
    { _Pragma("unroll")                                                                         \
      for (int j2 = 0; j2 < 2; ++j2)                                                            \
        _Pragma("unroll")                                                                       \
        for (int mt = 0; mt < 4; ++mt)                                                          \
          _Pragma("unroll")                                                                     \
          for (int nt = 0; nt < 4; ++nt)                                                        \
            acc[mt][nt] = __builtin_amdgcn_mfma_f32_16x16x32_f16(buf[j2*4+mt], wfh[(pr)*2+j2][nt], acc[mt][nt], 0, 0, 0); }

// Persistent kernel: all 511 timesteps, both directions.
// blockIdx = ntb*8 + group, group = dir*4 + mtblk. 1 block/CU forced by LDS size.
// W + c-state in registers. h exchanged via the group's shared XCD L2 when the
// runtime XCC_ID check confirms co-location; else via system-scope UC (original path).
__global__ __launch_bounds__(256, 1) void persistent_kernel(
    const int* __restrict__ xT, const _Float16* __restrict__ embh,
    const _Float16* __restrict__ Wpk, const float* __restrict__ biaspk,
    _Float16* __restrict__ hpk, float* __restrict__ hfinal,
    unsigned* __restrict__ bar, unsigned* __restrict__ xcdid)
{
    __shared__ float lds[4][64][LP_];

    int group = blockIdx.x & 7;
    int dir   = group >> 2;
    int mtblk = group & 3;
    int ntb   = blockIdx.x >> 3;
    int w    = threadIdx.x >> 6;
    int lane = threadIdx.x & 63;
    int q    = lane >> 4;
    int c16  = lane & 15;
    int u0   = q * 8;               // epilogue: 8 consecutive units per thread

    unsigned* gflags = bar + group * (32*16);

    // ---- publish this block's XCD id (system scope, one-time) ----
    unsigned myxcc;
    asm volatile("s_getreg_b32 %0, hwreg(HW_REG_XCC_ID)" : "=s"(myxcc));
    myxcc &= 15u;
    if (threadIdx.x == 0)
        __hip_atomic_store(&xcdid[blockIdx.x], myxcc | 0x100u, __ATOMIC_RELAXED, __HIP_MEMORY_SCOPE_SYSTEM);

    const _Float16* Wd = Wpk + (size_t)dir * (KB_*NTF_*512);

    // ---- preload W fragments into registers ----
    // wave w: x-kbs {2w, 2w+1}, h-kbs {8+8w .. 15+8w}
    half8 wfx[2][4], wfh[8][4];
    #pragma unroll
    for (int kx = 0; kx < 2; ++kx) {
        #pragma unroll
        for (int nt = 0; nt < 4; ++nt)
            wfx[kx][nt] = *(const half8*)(Wd + (((size_t)(2*w + kx)*NTF_ + (ntb*4 + nt))*64 + lane)*8);
    }
    #pragma unroll
    for (int i = 0; i < 8; ++i) {
        #pragma unroll
        for (int nt = 0; nt < 4; ++nt)
            wfh[i][nt] = *(const half8*)(Wd + (((size_t)(8 + 8*w + i)*NTF_ + (ntb*4 + nt))*64 + lane)*8);
    }

    // ---- preload epilogue biases ----
    float bgr[8], bir[8];
    #pragma unroll
    for (int j = 0; j < 8; ++j) {
        bgr[j] = biaspk[dir*NPK_ + ntb*64 + u0 + j];
        bir[j] = biaspk[dir*NPK_ + ntb*64 + 32 + u0 + j];
    }

    // ---- runtime co-location check: my group's 32 producers all on my XCD? ----
    bool fast;
    {
        unsigned idv = myxcc | 0x100u;   // lanes >= 32: passes both checks
        for (;;) {
            if (lane < 32)
                idv = __hip_atomic_load(&xcdid[lane*8 + group], __ATOMIC_RELAXED, __HIP_MEMORY_SCOPE_SYSTEM);
            if (__all(idv >= 0x100u)) break;
            __builtin_amdgcn_s_sleep(1);
        }
        fast = __all(idv == (myxcc | 0x100u));  // group-consistent decision
    }

    // ---- c-state in registers: thread owns (m = mtblk*64+w*16+c16, u = ntb*32+u0+j) ----
    float creg[8];
    #pragma unroll
    for (int j = 0; j < 8; ++j) creg[j] = 0.f;

    #pragma unroll 1
    for (int t = 0; t < S_; ++t) {
        const _Float16* hrd = hpk + (size_t)(t & 1) * HPK_PER_PAR + dir*(32*16*64*8);
        _Float16*       hwr = hpk + (size_t)((t & 1) ^ 1) * HPK_PER_PAR + dir*(32*16*64*8);
        int t_eff = dir ? (S_ - 1 - t) : t;

        int xr[4];
        #pragma unroll
        for (int mt = 0; mt < 4; ++mt)
            xr[mt] = xT[t_eff*B_ + mtblk*64 + mt*16 + c16];

        f32x4 acc[4][4];
        #pragma unroll
        for (int a = 0; a < 4; ++a)
            #pragma unroll
            for (int b = 0; b < 4; ++b) {
                acc[a][b][0] = 0.f; acc[a][b][1] = 0.f; acc[a][b][2] = 0.f; acc[a][b][3] = 0.f;
            }

        // ---- x-part (independent of h): overlaps producer wait ----
        #pragma unroll
        for (int kx = 0; kx < 2; ++kx) {
            int kb = 2*w + kx;
            half8 a[4];
            #pragma unroll
            for (int mt = 0; mt < 4; ++mt)
                a[mt] = *(const half8*)(embh + xr[mt]*D_ + kb*32 + q*8);
            #pragma unroll
            for (int mt = 0; mt < 4; ++mt) {
                #pragma unroll
                for (int nt = 0; nt < 4; ++nt)
                    acc[mt][nt] = __builtin_amdgcn_mfma_f32_16x16x32_f16(a[mt], wfx[kx][nt], acc[mt][nt], 0, 0, 0);
            }
        }

        if (t > 0) {
            unsigned gen = (unsigned)t;
            if (fast) {
                // ---- L2-scope wait: poll per-wave flags (4 words per producer line) ----
                u32x4 fv = {gen, gen, gen, gen};
                for (;;) {
                    if (lane < 32) {
                        const unsigned* fp = gflags + lane*16;
                        asm volatile("global_load_dwordx4 %0, %1, off sc0\n\ts_waitcnt vmcnt(0)"
                                     : "=v"(fv) : "v"(fp) : "memory");
                    }
                    if (__all(fv[0] >= gen && fv[1] >= gen && fv[2] >= gen && fv[3] >= gen)) break;
                    __builtin_amdgcn_s_sleep(1);
                }
                // ---- h-part: sc0 (L2-hit) loads, 2-deep pipelined with counted vmcnt ----
                half8 aE[8], aO[8];
                ISSUE_PAIR(aE, 0);
                ISSUE_PAIR(aO, 1);
                asm volatile("s_waitcnt vmcnt(8)" ::: "memory");
                __builtin_amdgcn_sched_barrier(0);
                MFMA_PAIR(aE, 0);
                ISSUE_PAIR(aE, 2);
                asm volatile("s_waitcnt vmcnt(8)" ::: "memory");
                __builtin_amdgcn_sched_barrier(0);
                MFMA_PAIR(aO, 1);
                ISSUE_PAIR(aO, 3);
                asm volatile("s_waitcnt vmcnt(8)" ::: "memory");
                __builtin_amdgcn_sched_barrier(0);
                MFMA_PAIR(aE, 2);
                asm volatile("s_waitcnt vmcnt(0)" ::: "memory");
                __builtin_amdgcn_sched_barrier(0);
                MFMA_PAIR(aO, 3);
            } else {
                // ---- system-scope fallback (original path) ----
                unsigned v = gen;
                for (;;) {
                    if (lane < 32)
                        v = __hip_atomic_load(&gflags[lane*16], __ATOMIC_RELAXED, __HIP_MEMORY_SCOPE_SYSTEM);
                    if (__all(v >= gen)) break;
                    __builtin_amdgcn_s_sleep(1);
                }
                #pragma unroll
                for (int i = 0; i < 8; ++i) {
                    int kb2 = 8*w + i;
                    half8 a[4];
                    #pragma unroll
                    for (int mt = 0; mt < 4; ++mt)
                        a[mt] = load_h_uc(hrd + (size_t)((kb2*16 + (mtblk*4 + mt))*64 + lane)*8);
                    #pragma unroll
                    for (int mt = 0; mt < 4; ++mt) {
                        #pragma unroll
                        for (int nt = 0; nt < 4; ++nt)
                            acc[mt][nt] = __builtin_amdgcn_mfma_f32_16x16x32_f16(a[mt], wfh[i][nt], acc[mt][nt], 0, 0, 0);
                    }
                }
            }
        }

        // K-split partials -> LDS
        #pragma unroll
        for (int mt = 0; mt < 4; ++mt) {
            #pragma unroll
            for (int nt = 0; nt < 4; ++nt) {
                #pragma unroll
                for (int r = 0; r < 4; ++r)
                    lds[w][mt*16 + q*4 + r][nt*16 + c16] = acc[mt][nt][r];
            }
        }
        __syncthreads();

        // Epilogue: thread -> (m_loc = w*16 + c16, units u0..u0+7). Cols: g = u_loc, i = 32+u_loc.
        {
            int mloc = w*16 + c16;
            int mg   = mtblk*64 + mloc;
            half8 hv;
            float hf[8];
            #pragma unroll
            for (int j = 0; j < 8; ++j) {
                float zg = lds[0][mloc][u0 + j] + lds[1][mloc][u0 + j]
                         + lds[2][mloc][u0 + j] + lds[3][mloc][u0 + j] + bgr[j];
                float zi = lds[0][mloc][32 + u0 + j] + lds[1][mloc][32 + u0 + j]
                         + lds[2][mloc][32 + u0 + j] + lds[3][mloc][32 + u0 + j] + bir[j];
                float g  = fast_tanh(zg);
                float ii = fast_sigm(zi);
                float cn = ii * (g + creg[j]);
                creg[j] = cn;
                float h = fast_tanh(cn) * ii;
                hv[j] = (_Float16)h;
                hf[j] = h;
            }
            // publish h into A-fragment layout
            _Float16* base = hwr + ((size_t)((ntb*16 + mtblk*4 + w)*64 + lane) * 8);
            if (fast) {
                // plain store -> lands in the group's shared XCD L2
                asm volatile("global_store_dwordx4 %0, %1, off" :: "v"(base), "v"(hv) : "memory");
            } else {
                u64 two[2];
                __builtin_memcpy(two, &hv, 16);
                __hip_atomic_store((u64*)base,     two[0], __ATOMIC_RELAXED, __HIP_MEMORY_SCOPE_SYSTEM);
                __hip_atomic_store((u64*)base + 1, two[1], __ATOMIC_RELAXED, __HIP_MEMORY_SCOPE_SYSTEM);
            }
            if (t == S_ - 1) {
                #pragma unroll
                for (int j = 0; j < 8; ++j)
                    hfinal[dir*(B_*H_) + mg*H_ + ntb*32 + u0 + j] = hf[j];
            }
        }

        // ---- publish completion flag ----
        if (t != S_ - 1) {
            if (fast) {
                // per-wave flag: only this wave's store must drain; no block barrier on the
                // signal path. LDS-protect barrier moved after the publish.
                asm volatile("s_waitcnt vmcnt(0)" ::: "memory");
                if (lane == 0) {
                    unsigned* fp = &gflags[ntb*16 + w];
                    unsigned val = (unsigned)(t + 1);
                    asm volatile("global_store_dword %0, %1, off" :: "v"(fp), "v"(val) : "memory");
                }
                __syncthreads();
            } else {
                __builtin_amdgcn_s_waitcnt(0x0F70);   // vmcnt(0)
                __syncthreads();
                if (threadIdx.x == 0)
                    __hip_atomic_store(&gflags[ntb*16], (unsigned)(t + 1), __ATOMIC_RELAXED, __HIP_MEMORY_SCOPE_SYSTEM);
            }
        }
    }
}

// out[b][c] = [hf|hb] @ Wp + bp
__global__ void proj_kernel(const float* __restrict__ hfinal,
                            const float* __restrict__ Wp, const float* __restrict__ bp,
                            float* __restrict__ out)
{
    int b = blockIdx.x;
    int lane = threadIdx.x;
    float s[C_];
    #pragma unroll
    for (int c = 0; c < C_; ++c) s[c] = 0.f;
    for (int j = lane; j < 2*H_; j += 64) {
        float hv = (j < H_) ? hfinal[b*H_ + j] : hfinal[B_*H_ + b*H_ + (j - H_)];
        const float* wr = Wp + j*C_;
        #pragma unroll
        for (int c = 0; c < C_; ++c) s[c] += hv * wr[c];
    }
    #pragma unroll
    for (int off = 32; off > 0; off >>= 1) {
        #pragma unroll
        for (int c = 0; c < C_; ++c) s[c] += __shfl_down(s[c], off);
    }
    if (lane == 0) {
        #pragma unroll
        for (int c = 0; c < C_; ++c) out[b*C_ + c] = s[c] + bp[c];
    }
}

extern "C" void kernel_launch(void* const* d_in, const int* in_sizes, int n_in,
                              void* d_out, int out_size, void* d_ws, size_t ws_size,
                              hipStream_t stream)
{
    const int*   x     = (const int*)d_in[0];
    const float* emb   = (const float*)d_in[1];
    const float* Wgx_f = (const float*)d_in[2];
    const float* Wgh_f = (const float*)d_in[3];
    const float* bg_f  = (const float*)d_in[4];
    const float* Wix_f = (const float*)d_in[5];
    const float* Wih_f = (const float*)d_in[6];
    const float* bi_f  = (const float*)d_in[7];
    const float* Wgx_b = (const float*)d_in[8];
    const float* Wgh_b = (const float*)d_in[9];
    const float* bg_b  = (const float*)d_in[10];
    const float* Wix_b = (const float*)d_in[11];
    const float* Wih_b = (const float*)d_in[12];
    const float* bi_b  = (const float*)d_in[13];
    const float* Wp    = (const float*)d_in[14];
    const float* bp    = (const float*)d_in[15];
    float* out = (float*)d_out;

    char* ws = (char*)d_ws;
    _Float16* Wpk    = (_Float16*)(ws + 0);
    _Float16* embh   = (_Float16*)(ws + EMBH_OFF);
    _Float16* hpk    = (_Float16*)(ws + HPK_OFF);
    float*    hfinal = (float*)(ws + HFIN_OFF);
    float*    biaspk = (float*)(ws + BIAS_OFF);
    unsigned* bar    = (unsigned*)(ws + BAR_OFF);
    int*      xT     = (int*)(ws + XT_OFF);
    unsigned* xcdid  = (unsigned*)(ws + XCD_OFF);

    int total = WPK_HALVES + EMBH_HALVES + 2*NPK_ + BAR_WORDS + XT_INTS + XCD_WORDS;
    convert_kernel<<<(total + 255)/256, 256, 0, stream>>>(
        x, emb, Wgx_f, Wgh_f, bg_f, Wix_f, Wih_f, bi_f,
        Wgx_b, Wgh_b, bg_b, Wix_b, Wih_b, bi_b, Wpk, embh, biaspk, bar, xT, xcdid);

    persistent_kernel<<<256, 256, 0, stream>>>(xT, embh, Wpk, biaspk, hpk, hfinal, bar, xcdid);

    proj_kernel<<<B_, 64, 0, stream>>>(hfinal, Wp, bp, out);
}

// Round 7
// 2449.616 us; speedup vs baseline: 1.8616x; 1.0371x over previous
//
#include <hip/hip_runtime.h>
#include <hip/hip_fp16.h>

typedef _Float16 half8 __attribute__((ext_vector_type(8)));
typedef float f32x4 __attribute__((ext_vector_type(4)));
typedef unsigned u32x4 __attribute__((ext_vector_type(4)));
typedef unsigned long long u64;

#define B_ 256
#define SEQ_ 512
#define D_ 256
#define H_ 1024
#define C_ 10
#define S_ 511
#define KB_ 40      // K=1280 / 32
#define NPK_ 2048   // packed output cols per direction (g|i interleaved per 64)
#define NTF_ 128    // NPK/16 fine n-tiles
#define LP_ 84      // LDS row stride (floats): 86,016B total -> forces 1 block/CU (co-residency guarantee)

// ---- workspace byte offsets ----
#define WPK_HALVES (2*KB_*NTF_*512)                    // 5,242,880 halves
#define EMBH_OFF   (WPK_HALVES*2)                      // 10,485,760
#define EMBH_HALVES (SEQ_*D_)                          // 131,072
#define HPK_OFF    (EMBH_OFF + EMBH_HALVES*2)          // 10,747,904
#define HPK_PER_PAR (2*32*16*64*8)                     // 524,288 halves per parity (both dirs)
#define HFIN_OFF   (HPK_OFF + 2*HPK_PER_PAR*2)         // 12,845,056
#define HFIN_FLOATS (2*B_*H_)
#define BIAS_OFF   (HFIN_OFF + HFIN_FLOATS*4)
#define BAR_OFF    (BIAS_OFF + 2*NPK_*4)               // 8 groups x 32 producers x 16-word pad (words 0..3 used)
#define BAR_WORDS  (8*32*16)
#define XT_OFF     (BAR_OFF + BAR_WORDS*4)             // transposed x: [SEQ][B] ints
#define XT_INTS    (SEQ_*B_)
#define XCD_OFF    (XT_OFF + XT_INTS*4)                // per-block XCC id (runtime co-location check)
#define XCD_WORDS  256

__device__ __forceinline__ float fast_sigm(float x) {
    return __builtin_amdgcn_rcpf(1.f + __builtin_amdgcn_exp2f(-1.442695041f * x));
}
__device__ __forceinline__ float fast_tanh(float x) {
    return 1.f - 2.f * __builtin_amdgcn_rcpf(1.f + __builtin_amdgcn_exp2f(2.885390082f * x));
}
__device__ __forceinline__ half8 load_h_uc(const _Float16* p) {
    u64 two[2];
    two[0] = __hip_atomic_load((const u64*)p,     __ATOMIC_RELAXED, __HIP_MEMORY_SCOPE_SYSTEM);
    two[1] = __hip_atomic_load((const u64*)p + 1, __ATOMIC_RELAXED, __HIP_MEMORY_SCOPE_SYSTEM);
    half8 r; __builtin_memcpy(&r, two, 16); return r;
}

// Pack fp32 weights -> fp16 MFMA B-fragment-direct layout, emb -> fp16, biases packed,
// x -> transposed xT[t][m], zero barrier flags + xcd-id slots (ws is re-poisoned before every call).
__global__ void convert_kernel(
    const int* __restrict__ x, const float* __restrict__ emb,
    const float* __restrict__ Wgx_f, const float* __restrict__ Wgh_f, const float* __restrict__ bg_f,
    const float* __restrict__ Wix_f, const float* __restrict__ Wih_f, const float* __restrict__ bi_f,
    const float* __restrict__ Wgx_b, const float* __restrict__ Wgh_b, const float* __restrict__ bg_b,
    const float* __restrict__ Wix_b, const float* __restrict__ Wih_b, const float* __restrict__ bi_b,
    _Float16* __restrict__ Wpk, _Float16* __restrict__ embh, float* __restrict__ biaspk,
    unsigned* __restrict__ bar, int* __restrict__ xT, unsigned* __restrict__ xcdid)
{
    int idx = blockIdx.x * 256 + threadIdx.x;
    if (idx < WPK_HALVES) {
        int j = idx & 7;
        int L = (idx >> 3) & 63;
        int rest = idx >> 9;
        int ntf = rest & (NTF_ - 1);
        int rest2 = rest >> 7;
        int kb = rest2 % KB_;
        int d  = rest2 / KB_;
        int k = kb*32 + ((L >> 4) << 3) + j;
        int p = (ntf << 4) + (L & 15);
        int gate = (p >> 5) & 1;
        int u = ((p >> 6) << 5) + (p & 31);
        float v;
        if (k < D_) {
            const float* W = d ? (gate ? Wix_b : Wgx_b) : (gate ? Wix_f : Wgx_f);
            v = W[k*H_ + u];
        } else {
            const float* W = d ? (gate ? Wih_b : Wgh_b) : (gate ? Wih_f : Wgh_f);
            v = W[(k - D_)*H_ + u];
        }
        Wpk[idx] = (_Float16)v;
    } else if (idx < WPK_HALVES + EMBH_HALVES) {
        int i2 = idx - WPK_HALVES;
        embh[i2] = (_Float16)emb[i2];
    } else if (idx < WPK_HALVES + EMBH_HALVES + 2*NPK_) {
        int i3 = idx - (WPK_HALVES + EMBH_HALVES);
        int d = i3 >> 11;
        int p = i3 & (NPK_ - 1);
        int gate = (p >> 5) & 1;
        int u = ((p >> 6) << 5) + (p & 31);
        const float* bsrc = d ? (gate ? bi_b : bg_b) : (gate ? bi_f : bg_f);
        biaspk[i3] = bsrc[u];
    } else if (idx < WPK_HALVES + EMBH_HALVES + 2*NPK_ + BAR_WORDS) {
        bar[idx - (WPK_HALVES + EMBH_HALVES + 2*NPK_)] = 0u;
    } else if (idx < WPK_HALVES + EMBH_HALVES + 2*NPK_ + BAR_WORDS + XT_INTS) {
        int i5 = idx - (WPK_HALVES + EMBH_HALVES + 2*NPK_ + BAR_WORDS);
        int t = i5 >> 8;
        int m = i5 & (B_ - 1);
        xT[i5] = x[m*SEQ_ + t];
    } else if (idx < WPK_HALVES + EMBH_HALVES + 2*NPK_ + BAR_WORDS + XT_INTS + XCD_WORDS) {
        xcdid[idx - (WPK_HALVES + EMBH_HALVES + 2*NPK_ + BAR_WORDS + XT_INTS)] = 0u;
    }
}

// Fast-path L2-scope exchange helpers. Group blocks share one XCD (runtime-verified).
// h-sweep order is rotated by ntb (ir = (idx + ntb) & 7) so the 32 consumer blocks do not
// all hit the same L2 lines simultaneously; wfh[] preload is rotated identically so all
// MFMA register indices stay compile-time static (no scratch).
#define ISSUE_PAIR(buf, pr)                                                                     \
    { _Pragma("unroll")                                                                         \
      for (int j2 = 0; j2 < 2; ++j2) {                                                          \
        int ir = ((pr)*2 + j2 + ntb) & 7;                                                       \
        _Pragma("unroll")                                                                       \
        for (int mt = 0; mt < 4; ++mt) {                                                        \
            const _Float16* hp = hrd + (size_t)(((8*w + ir)*16 + (mtblk*4 + mt))*64 + lane)*8;  \
            asm volatile("global_load_dwordx4 %0, %1, off sc0" : "=v"(buf[j2*4+mt]) : "v"(hp)); \
        } } }

#define MFMA_PAIR(buf, pr)                                                                      \
    { _Pragma("unroll")                                                                         \
      for (int j2 = 0; j2 < 2; ++j2)                                                            \
        _Pragma("unroll")                                                                       \
        for (int mt = 0; mt < 4; ++mt)                                                          \
          _Pragma("unroll")                                                                     \
          for (int nt = 0; nt < 4; ++nt)                                                        \
            acc[mt][nt] = __builtin_amdgcn_mfma_f32_16x16x32_f16(buf[j2*4+mt], wfh[(pr)*2+j2][nt], acc[mt][nt], 0, 0, 0); }

// Persistent kernel: all 511 timesteps, both directions.
// blockIdx = ntb*8 + group, group = dir*4 + mtblk. 1 block/CU forced by LDS size.
// W + c-state in registers. h exchanged via the group's shared XCD L2 when the
// runtime XCC_ID check confirms co-location; else via system-scope UC.
// vs round-1: (a) per-wave poll of only the 8 producers this wave consumes (kb2=8w+i
// -> ntb in [8w,8w+8)) -- 4x less flag traffic, max-of-8 not max-of-32 wait;
// (b) ntb-rotated h-sweep; (c) vectorized b128 epilogue reduce.
__global__ __launch_bounds__(256, 1) void persistent_kernel(
    const int* __restrict__ xT, const _Float16* __restrict__ embh,
    const _Float16* __restrict__ Wpk, const float* __restrict__ biaspk,
    _Float16* __restrict__ hpk, float* __restrict__ hfinal,
    unsigned* __restrict__ bar, unsigned* __restrict__ xcdid)
{
    __shared__ float lds[4][64][LP_];

    int group = blockIdx.x & 7;
    int dir   = group >> 2;
    int mtblk = group & 3;
    int ntb   = blockIdx.x >> 3;
    int w    = threadIdx.x >> 6;
    int lane = threadIdx.x & 63;
    int q    = lane >> 4;
    int c16  = lane & 15;
    int u0   = q * 8;               // epilogue: 8 consecutive units per thread

    unsigned* gflags = bar + group * (32*16);

    // ---- publish this block's XCD id (system scope, one-time) ----
    unsigned myxcc;
    asm volatile("s_getreg_b32 %0, hwreg(HW_REG_XCC_ID)" : "=s"(myxcc));
    myxcc &= 15u;
    if (threadIdx.x == 0)
        __hip_atomic_store(&xcdid[blockIdx.x], myxcc | 0x100u, __ATOMIC_RELAXED, __HIP_MEMORY_SCOPE_SYSTEM);

    const _Float16* Wd = Wpk + (size_t)dir * (KB_*NTF_*512);

    // ---- preload W fragments into registers ----
    // wave w: x-kbs {2w, 2w+1}; h-kbs rotated: wfh[i] holds kb 8 + 8w + ((i+ntb)&7)
    half8 wfx[2][4], wfh[8][4];
    #pragma unroll
    for (int kx = 0; kx < 2; ++kx) {
        #pragma unroll
        for (int nt = 0; nt < 4; ++nt)
            wfx[kx][nt] = *(const half8*)(Wd + (((size_t)(2*w + kx)*NTF_ + (ntb*4 + nt))*64 + lane)*8);
    }
    #pragma unroll
    for (int i = 0; i < 8; ++i) {
        int ir = (i + ntb) & 7;
        #pragma unroll
        for (int nt = 0; nt < 4; ++nt)
            wfh[i][nt] = *(const half8*)(Wd + (((size_t)(8 + 8*w + ir)*NTF_ + (ntb*4 + nt))*64 + lane)*8);
    }

    // ---- preload epilogue biases ----
    float bgr[8], bir[8];
    #pragma unroll
    for (int j = 0; j < 8; ++j) {
        bgr[j] = biaspk[dir*NPK_ + ntb*64 + u0 + j];
        bir[j] = biaspk[dir*NPK_ + ntb*64 + 32 + u0 + j];
    }

    // ---- runtime co-location check: my group's 32 producers all on my XCD? ----
    bool fast;
    {
        unsigned idv = myxcc | 0x100u;   // lanes >= 32: passes both checks
        for (;;) {
            if (lane < 32)
                idv = __hip_atomic_load(&xcdid[lane*8 + group], __ATOMIC_RELAXED, __HIP_MEMORY_SCOPE_SYSTEM);
            if (__all(idv >= 0x100u)) break;
            __builtin_amdgcn_s_sleep(1);
        }
        fast = __all(idv == (myxcc | 0x100u));  // group-consistent decision
    }

    // ---- c-state in registers: thread owns (m = mtblk*64+w*16+c16, u = ntb*32+u0+j) ----
    float creg[8];
    #pragma unroll
    for (int j = 0; j < 8; ++j) creg[j] = 0.f;

    #pragma unroll 1
    for (int t = 0; t < S_; ++t) {
        const _Float16* hrd = hpk + (size_t)(t & 1) * HPK_PER_PAR + dir*(32*16*64*8);
        _Float16*       hwr = hpk + (size_t)((t & 1) ^ 1) * HPK_PER_PAR + dir*(32*16*64*8);
        int t_eff = dir ? (S_ - 1 - t) : t;

        int xr[4];
        #pragma unroll
        for (int mt = 0; mt < 4; ++mt)
            xr[mt] = xT[t_eff*B_ + mtblk*64 + mt*16 + c16];

        f32x4 acc[4][4];
        #pragma unroll
        for (int a = 0; a < 4; ++a)
            #pragma unroll
            for (int b = 0; b < 4; ++b) {
                acc[a][b][0] = 0.f; acc[a][b][1] = 0.f; acc[a][b][2] = 0.f; acc[a][b][3] = 0.f;
            }

        // ---- x-part (independent of h): overlaps producer wait ----
        #pragma unroll
        for (int kx = 0; kx < 2; ++kx) {
            int kb = 2*w + kx;
            half8 a[4];
            #pragma unroll
            for (int mt = 0; mt < 4; ++mt)
                a[mt] = *(const half8*)(embh + xr[mt]*D_ + kb*32 + q*8);
            #pragma unroll
            for (int mt = 0; mt < 4; ++mt) {
                #pragma unroll
                for (int nt = 0; nt < 4; ++nt)
                    acc[mt][nt] = __builtin_amdgcn_mfma_f32_16x16x32_f16(a[mt], wfx[kx][nt], acc[mt][nt], 0, 0, 0);
            }
        }

        if (t > 0) {
            unsigned gen = (unsigned)t;
            if (fast) {
                // ---- per-wave wait: only THIS wave's 8 producers (ntb' = 8w..8w+7),
                //      all 4 per-wave flag words each: lanes 0..31 -> (8w+(lane>>2), lane&3) ----
                unsigned v = gen;
                const unsigned* fp = gflags + (8*w + (lane >> 2))*16 + (lane & 3);
                for (;;) {
                    if (lane < 32)
                        asm volatile("global_load_dword %0, %1, off sc0\n\ts_waitcnt vmcnt(0)"
                                     : "=v"(v) : "v"(fp) : "memory");
                    if (__all(v >= gen)) break;
                    __builtin_amdgcn_s_sleep(1);
                }
                // ---- h-part: sc0 (L2-hit) loads, 2-deep pipelined with counted vmcnt ----
                half8 aE[8], aO[8];
                ISSUE_PAIR(aE, 0);
                ISSUE_PAIR(aO, 1);
                asm volatile("s_waitcnt vmcnt(8)" ::: "memory");
                __builtin_amdgcn_sched_barrier(0);
                MFMA_PAIR(aE, 0);
                ISSUE_PAIR(aE, 2);
                asm volatile("s_waitcnt vmcnt(8)" ::: "memory");
                __builtin_amdgcn_sched_barrier(0);
                MFMA_PAIR(aO, 1);
                ISSUE_PAIR(aO, 3);
                asm volatile("s_waitcnt vmcnt(8)" ::: "memory");
                __builtin_amdgcn_sched_barrier(0);
                MFMA_PAIR(aE, 2);
                asm volatile("s_waitcnt vmcnt(0)" ::: "memory");
                __builtin_amdgcn_sched_barrier(0);
                MFMA_PAIR(aO, 3);
            } else {
                // ---- system-scope fallback (block-granular word-0 flags; rotated sweep) ----
                unsigned v = gen;
                for (;;) {
                    if (lane < 32)
                        v = __hip_atomic_load(&gflags[lane*16], __ATOMIC_RELAXED, __HIP_MEMORY_SCOPE_SYSTEM);
                    if (__all(v >= gen)) break;
                    __builtin_amdgcn_s_sleep(1);
                }
                #pragma unroll
                for (int i = 0; i < 8; ++i) {
                    int kb2 = 8*w + ((i + ntb) & 7);
                    half8 a[4];
                    #pragma unroll
                    for (int mt = 0; mt < 4; ++mt)
                        a[mt] = load_h_uc(hrd + (size_t)((kb2*16 + (mtblk*4 + mt))*64 + lane)*8);
                    #pragma unroll
                    for (int mt = 0; mt < 4; ++mt) {
                        #pragma unroll
                        for (int nt = 0; nt < 4; ++nt)
                            acc[mt][nt] = __builtin_amdgcn_mfma_f32_16x16x32_f16(a[mt], wfh[i][nt], acc[mt][nt], 0, 0, 0);
                    }
                }
            }
        }

        // K-split partials -> LDS
        #pragma unroll
        for (int mt = 0; mt < 4; ++mt) {
            #pragma unroll
            for (int nt = 0; nt < 4; ++nt) {
                #pragma unroll
                for (int r = 0; r < 4; ++r)
                    lds[w][mt*16 + q*4 + r][nt*16 + c16] = acc[mt][nt][r];
            }
        }
        __syncthreads();

        // Epilogue: thread -> (m_loc = w*16 + c16, units u0..u0+7). Cols: g = u_loc, i = 32+u_loc.
        // Vectorized reduce: 16 ds_read_b128 (4 K-partials x {g-lo, g-hi, i-lo, i-hi}).
        {
            int mloc = w*16 + c16;
            int mg   = mtblk*64 + mloc;
            f32x4 sg0, sg1, si0, si1;
            {
                f32x4 g0a = *(const f32x4*)&lds[0][mloc][u0];
                f32x4 g0b = *(const f32x4*)&lds[1][mloc][u0];
                f32x4 g0c = *(const f32x4*)&lds[2][mloc][u0];
                f32x4 g0d = *(const f32x4*)&lds[3][mloc][u0];
                sg0 = (g0a + g0b) + (g0c + g0d);
                f32x4 g1a = *(const f32x4*)&lds[0][mloc][u0 + 4];
                f32x4 g1b = *(const f32x4*)&lds[1][mloc][u0 + 4];
                f32x4 g1c = *(const f32x4*)&lds[2][mloc][u0 + 4];
                f32x4 g1d = *(const f32x4*)&lds[3][mloc][u0 + 4];
                sg1 = (g1a + g1b) + (g1c + g1d);
                f32x4 i0a = *(const f32x4*)&lds[0][mloc][32 + u0];
                f32x4 i0b = *(const f32x4*)&lds[1][mloc][32 + u0];
                f32x4 i0c = *(const f32x4*)&lds[2][mloc][32 + u0];
                f32x4 i0d = *(const f32x4*)&lds[3][mloc][32 + u0];
                si0 = (i0a + i0b) + (i0c + i0d);
                f32x4 i1a = *(const f32x4*)&lds[0][mloc][36 + u0];
                f32x4 i1b = *(const f32x4*)&lds[1][mloc][36 + u0];
                f32x4 i1c = *(const f32x4*)&lds[2][mloc][36 + u0];
                f32x4 i1d = *(const f32x4*)&lds[3][mloc][36 + u0];
                si1 = (i1a + i1b) + (i1c + i1d);
            }
            float zg[8], zi[8];
            #pragma unroll
            for (int j = 0; j < 4; ++j) { zg[j]   = sg0[j] + bgr[j];   zi[j]   = si0[j] + bir[j]; }
            #pragma unroll
            for (int j = 0; j < 4; ++j) { zg[4+j] = sg1[j] + bgr[4+j]; zi[4+j] = si1[j] + bir[4+j]; }
            half8 hv;
            float hf[8];
            #pragma unroll
            for (int j = 0; j < 8; ++j) {
                float g  = fast_tanh(zg[j]);
                float ii = fast_sigm(zi[j]);
                float cn = ii * (g + creg[j]);
                creg[j] = cn;
                float h = fast_tanh(cn) * ii;
                hv[j] = (_Float16)h;
                hf[j] = h;
            }
            // publish h into A-fragment layout
            _Float16* base = hwr + ((size_t)((ntb*16 + mtblk*4 + w)*64 + lane) * 8);
            if (fast) {
                asm volatile("global_store_dwordx4 %0, %1, off" :: "v"(base), "v"(hv) : "memory");
            } else {
                u64 two[2];
                __builtin_memcpy(two, &hv, 16);
                __hip_atomic_store((u64*)base,     two[0], __ATOMIC_RELAXED, __HIP_MEMORY_SCOPE_SYSTEM);
                __hip_atomic_store((u64*)base + 1, two[1], __ATOMIC_RELAXED, __HIP_MEMORY_SCOPE_SYSTEM);
            }
            if (t == S_ - 1) {
                #pragma unroll
                for (int j = 0; j < 8; ++j)
                    hfinal[dir*(B_*H_) + mg*H_ + ntb*32 + u0 + j] = hf[j];
            }
        }

        // ---- publish completion flag ----
        if (t != S_ - 1) {
            if (fast) {
                // per-wave flag: only this wave's store must drain; block barrier
                // (LDS protect) is off the signal path.
                asm volatile("s_waitcnt vmcnt(0)" ::: "memory");
                if (lane == 0) {
                    unsigned* fp2 = &gflags[ntb*16 + w];
                    unsigned val = (unsigned)(t + 1);
                    asm volatile("global_store_dword %0, %1, off" :: "v"(fp2), "v"(val) : "memory");
                }
                __syncthreads();
            } else {
                __builtin_amdgcn_s_waitcnt(0x0F70);   // vmcnt(0)
                __syncthreads();
                if (threadIdx.x == 0)
                    __hip_atomic_store(&gflags[ntb*16], (unsigned)(t + 1), __ATOMIC_RELAXED, __HIP_MEMORY_SCOPE_SYSTEM);
            }
        }
    }
}

// out[b][c] = [hf|hb] @ Wp + bp
__global__ void proj_kernel(const float* __restrict__ hfinal,
                            const float* __restrict__ Wp, const float* __restrict__ bp,
                            float* __restrict__ out)
{
    int b = blockIdx.x;
    int lane = threadIdx.x;
    float s[C_];
    #pragma unroll
    for (int c = 0; c < C_; ++c) s[c] = 0.f;
    for (int j = lane; j < 2*H_; j += 64) {
        float hv = (j < H_) ? hfinal[b*H_ + j] : hfinal[B_*H_ + b*H_ + (j - H_)];
        const float* wr = Wp + j*C_;
        #pragma unroll
        for (int c = 0; c < C_; ++c) s[c] += hv * wr[c];
    }
    #pragma unroll
    for (int off = 32; off > 0; off >>= 1) {
        #pragma unroll
        for (int c = 0; c < C_; ++c) s[c] += __shfl_down(s[c], off);
    }
    if (lane == 0) {
        #pragma unroll
        for (int c = 0; c < C_; ++c) out[b*C_ + c] = s[c] + bp[c];
    }
}

extern "C" void kernel_launch(void* const* d_in, const int* in_sizes, int n_in,
                              void* d_out, int out_size, void* d_ws, size_t ws_size,
                              hipStream_t stream)
{
    const int*   x     = (const int*)d_in[0];
    const float* emb   = (const float*)d_in[1];
    const float* Wgx_f = (const float*)d_in[2];
    const float* Wgh_f = (const float*)d_in[3];
    const float* bg_f  = (const float*)d_in[4];
    const float* Wix_f = (const float*)d_in[5];
    const float* Wih_f = (const float*)d_in[6];
    const float* bi_f  = (const float*)d_in[7];
    const float* Wgx_b = (const float*)d_in[8];
    const float* Wgh_b = (const float*)d_in[9];
    const float* bg_b  = (const float*)d_in[10];
    const float* Wix_b = (const float*)d_in[11];
    const float* Wih_b = (const float*)d_in[12];
    const float* bi_b  = (const float*)d_in[13];
    const float* Wp    = (const float*)d_in[14];
    const float* bp    = (const float*)d_in[15];
    float* out = (float*)d_out;

    char* ws = (char*)d_ws;
    _Float16* Wpk    = (_Float16*)(ws + 0);
    _Float16* embh   = (_Float16*)(ws + EMBH_OFF);
    _Float16* hpk    = (_Float16*)(ws + HPK_OFF);
    float*    hfinal = (float*)(ws + HFIN_OFF);
    float*    biaspk = (float*)(ws + BIAS_OFF);
    unsigned* bar    = (unsigned*)(ws + BAR_OFF);
    int*      xT     = (int*)(ws + XT_OFF);
    unsigned* xcdid  = (unsigned*)(ws + XCD_OFF);

    int total = WPK_HALVES + EMBH_HALVES + 2*NPK_ + BAR_WORDS + XT_INTS + XCD_WORDS;
    convert_kernel<<<(total + 255)/256, 256, 0, stream>>>(
        x, emb, Wgx_f, Wgh_f, bg_f, Wix_f, Wih_f, bi_f,
        Wgx_b, Wgh_b, bg_b, Wix_b, Wih_b, bi_b, Wpk, embh, biaspk, bar, xT, xcdid);

    persistent_kernel<<<256, 256, 0, stream>>>(xT, embh, Wpk, biaspk, hpk, hfinal, bar, xcdid);

    proj_kernel<<<B_, 64, 0, stream>>>(hfinal, Wp, bp, out);
}